// Round 4
// baseline (239.170 us; speedup 1.0000x reference)
//
#include <hip/hip_runtime.h>
#include <hip/hip_bf16.h>

typedef unsigned short u16;
typedef unsigned int u32;
typedef __attribute__((ext_vector_type(8))) __bf16 bf16x8;
typedef __attribute__((ext_vector_type(4))) float f32x4;
typedef __attribute__((ext_vector_type(16))) float f32x16;
typedef __attribute__((ext_vector_type(4))) u32 u32x4;

#define DEVFN static __device__ __forceinline__

DEVFN float bf2f(u16 v) { union { u32 u; float f; } x; x.u = (u32)v << 16; return x.f; }
DEVFN u16 f2bf(float f) {
    union { float f; u32 u; } x; x.f = f;
    u32 r = x.u + 0x7fff + ((x.u >> 16) & 1);
    return (u16)(r >> 16);
}

union BF2 { struct { __bf16 lo, hi; } s; u32 w; };
DEVFN u32 pk2(float a, float b) { BF2 t; t.s.lo = (__bf16)a; t.s.hi = (__bf16)b; return t.w; }

DEVFN void gload_lds16(const u16* g, u16* l) {
    __builtin_amdgcn_global_load_lds((const __attribute__((address_space(1))) u32*)g,
                                     (__attribute__((address_space(3))) u32*)l, 16, 0, 0);
}

// ---------------------------------------------------------------------------
// Generic C = A (M,K) @ B^T (N,K), bf16 in, f32 accum.
// OUTMODE: 0 = bf16 C; 1 = f32 C (+opt f32 bias/residual); 2 = bf16 Vt store
// ---------------------------------------------------------------------------
template<int BN, int OUTMODE, bool BIAS, bool RES>
__global__ __launch_bounds__(256)
void gemm_bt(const u16* __restrict__ A, const u16* __restrict__ B,
             void* __restrict__ Cv, const float* __restrict__ bias,
             const float* __restrict__ res,
             int K, int lda, int ldb, int ldc,
             long sAb, long sAh, long sBb, long sBh, long sCb, long sCh,
             float scale)
{
    constexpr int NF = BN / 32;  // n-frags per wave
    __shared__ u16 smem[4096 + BN * 32];
    const int tid = threadIdx.x;
    const int lane = tid & 63, wave = tid >> 6;
    const int wr = wave >> 1, wc = wave & 1;
    const int z = blockIdx.z, zb = z >> 3, zh = z & 7;

    const u16* Ab = A + zb * sAb + zh * sAh + (long)blockIdx.x * 128 * lda;
    const u16* Bb = B + zb * sBb + zh * sBh + (long)blockIdx.y * BN * ldb;

    const int ra = tid >> 2, ca = (tid & 3) * 8;
    const u16* pA0 = Ab + (long)ra * lda + ca;
    const u16* pA1 = Ab + (long)(ra + 64) * lda + ca;
    u16* lA0 = smem + tid * 8;
    u16* lA1 = smem + (256 + tid) * 8;
    const u16* pB0 = Bb + (long)ra * ldb + ca;
    const u16* pB1 = Bb + (long)(ra + 64) * ldb + ca;
    u16* lB0 = smem + 4096 + tid * 8;
    u16* lB1 = smem + 4096 + (256 + tid) * 8;

    const int foff = ((lane & 15) * 4 + (lane >> 4)) * 8;  // frag offset (u16)
    const u16* aF = smem + wr * 2048 + foff;
    const u16* bF = smem + 4096 + wc * (NF * 512) + foff;

    f32x4 acc[4][NF];
#pragma unroll
    for (int i = 0; i < 4; ++i)
#pragma unroll
        for (int j = 0; j < NF; ++j) acc[i][j] = (f32x4){0.f, 0.f, 0.f, 0.f};

    for (int k0 = 0; k0 < K; k0 += 32) {
        gload_lds16(pA0 + k0, lA0);
        gload_lds16(pA1 + k0, lA1);
        gload_lds16(pB0 + k0, lB0);
        if constexpr (BN == 128) gload_lds16(pB1 + k0, lB1);
        asm volatile("s_waitcnt vmcnt(0)" ::: "memory");
        __syncthreads();
        bf16x8 av[4], bv[NF];
#pragma unroll
        for (int i = 0; i < 4; ++i) av[i] = *(const bf16x8*)(aF + i * 512);
#pragma unroll
        for (int j = 0; j < NF; ++j) bv[j] = *(const bf16x8*)(bF + j * 512);
#pragma unroll
        for (int i = 0; i < 4; ++i)
#pragma unroll
            for (int j = 0; j < NF; ++j)
                acc[i][j] = __builtin_amdgcn_mfma_f32_16x16x32_bf16(av[i], bv[j], acc[i][j], 0, 0, 0);
        __syncthreads();
    }

    const int m0 = blockIdx.x * 128 + wr * 64 + (lane >> 4) * 4;
    const int n0 = blockIdx.y * BN + wc * (BN / 2) + (lane & 15);
    if constexpr (OUTMODE == 0) {
        u16* Cb = (u16*)Cv + zb * sCb + zh * sCh;
#pragma unroll
        for (int i = 0; i < 4; ++i)
#pragma unroll
            for (int j = 0; j < NF; ++j) {
                int n = n0 + j * 16;
#pragma unroll
                for (int r = 0; r < 4; ++r) {
                    int m = m0 + i * 16 + r;
                    Cb[(long)m * ldc + n] = f2bf(acc[i][j][r] * scale);
                }
            }
    } else if constexpr (OUTMODE == 1) {
        float* Cb = (float*)Cv + zb * sCb + zh * sCh;
#pragma unroll
        for (int i = 0; i < 4; ++i)
#pragma unroll
            for (int j = 0; j < NF; ++j) {
                int n = n0 + j * 16;
                float bv_ = BIAS ? bias[n] : 0.f;
#pragma unroll
                for (int r = 0; r < 4; ++r) {
                    int m = m0 + i * 16 + r;
                    float v = acc[i][j][r] * scale + bv_;
                    if constexpr (RES) v += res[(long)m * ldc + n];
                    Cb[(long)m * ldc + n] = v;
                }
            }
    } else {
        // store V transposed: Vt[(b*8+h)][d][s]; m=b*256+s, n=h*64+d
#pragma unroll
        for (int i = 0; i < 4; ++i) {
            int m = m0 + i * 16;
            int b = m >> 8, s = m & 255;
#pragma unroll
            for (int j = 0; j < NF; ++j) {
                int n = n0 + j * 16;
                int h = n >> 6, d = n & 63;
                ushort4 pk;
                pk.x = f2bf(acc[i][j][0]); pk.y = f2bf(acc[i][j][1]);
                pk.z = f2bf(acc[i][j][2]); pk.w = f2bf(acc[i][j][3]);
                *(ushort4*)((u16*)Cv + (((long)(b * 8 + h) * 64 + d) * 256 + s)) = pk;
            }
        }
    }
}

// ---------------------------------------------------------------------------
// Fused attention, online-softmax, no K/V LDS staging (K/V are L2-resident).
// grid (32 qchunks, 64 bh), 4 waves x 32 queries. Swapped QK^T (S^T = K@Q)
// in log2 domain (Q pre-scaled by 0.125*log2e); per-32-key tile: tile-max,
// defer-max rescale (THR=8), exp2, pack to bf16 (hw cvt), half-swap via
// shfl_xor (R3-validated mapping), PV mfma with V^T frags from global.
// Epilogue: normalize, transpose via per-wave swizzled LDS, coalesced store.
// ---------------------------------------------------------------------------
union U8 { u32 w[4]; bf16x8 v; };

__global__ __launch_bounds__(256, 3)
void attn_fused(const u16* __restrict__ Q, const u16* __restrict__ K,
                const u16* __restrict__ Vt, u16* __restrict__ O)
{
    __shared__ u16 lds[8192];  // 16KB: 4KB per-wave epilogue scratch
    const int tid = threadIdx.x, lane = tid & 63, wave = tid >> 6;
    const int bh = blockIdx.y, b = bh >> 3, h = bh & 7;
    const int l31 = lane & 31, lh = lane >> 5;
    const long q0 = (long)b * 4096 + blockIdx.x * 128 + wave * 32;
    const bool hiHalf = (lh != 0);

    // Q B-frags (col=q=lane&31, k=kc*16+lh*8+j), loaded once
    bf16x8 qf[4];
    {
        const u16* Qp = Q + (q0 + l31) * 512 + h * 64 + lh * 8;
#pragma unroll
        for (int kc = 0; kc < 4; ++kc) qf[kc] = *(const bf16x8*)(Qp + kc * 16);
    }
    const u16* Kp = K + ((long)b * 256 + l31) * 512 + h * 64 + lh * 8;
    const u16* Vp = Vt + (long)bh * 16384 + (long)l31 * 256 + lh * 8;

    f32x16 oacc[2];
#pragma unroll
    for (int dt = 0; dt < 2; ++dt)
#pragma unroll
        for (int r = 0; r < 16; ++r) oacc[dt][r] = 0.f;
    float m_run = -3e38f, sum_run = 0.f;

#pragma unroll
    for (int st = 0; st < 8; ++st) {
        // ---- QK^T tile: S^T[s=st*32+..][q], C row=(r&3)+8*(r>>2)+4*lh, col=l31
        f32x16 sc;
#pragma unroll
        for (int r = 0; r < 16; ++r) sc[r] = 0.f;
#pragma unroll
        for (int kc = 0; kc < 4; ++kc) {
            bf16x8 af = *(const bf16x8*)(Kp + (long)st * 16384 + kc * 16);
            sc = __builtin_amdgcn_mfma_f32_32x32x16_bf16(af, qf[kc], sc, 0, 0, 0);
        }
        // ---- tile max (in-lane 16 + pair lane^32)
        float tm = sc[0];
#pragma unroll
        for (int r = 1; r < 16; ++r) tm = fmaxf(tm, sc[r]);
        tm = fmaxf(tm, __shfl_xor(tm, 32));
        // ---- defer-max: rescale only when tile max grew past THR=8 (log2)
        if (!__all(tm <= m_run + 8.f)) {
            float mnew = fmaxf(m_run, tm);
            float fac = exp2f(m_run - mnew);
            m_run = mnew;
            sum_run *= fac;
#pragma unroll
            for (int dt = 0; dt < 2; ++dt)
#pragma unroll
                for (int r = 0; r < 16; ++r) oacc[dt][r] *= fac;
        }
        // ---- P = exp2(S' - m), in place
#pragma unroll
        for (int r = 0; r < 16; ++r) {
            float e = exp2f(sc[r] - m_run);
            sc[r] = e; sum_run += e;
        }
        // ---- pack to bf16 pairs + half-swap (R3-validated mapping)
        u32 c[8], x[8];
#pragma unroll
        for (int i = 0; i < 8; ++i) c[i] = pk2(sc[2 * i], sc[2 * i + 1]);
#pragma unroll
        for (int i = 0; i < 8; ++i) x[i] = (u32)__shfl_xor((int)c[i], 32);
        U8 p0, p1;
        p0.w[0] = hiHalf ? x[2] : c[0];  p0.w[1] = hiHalf ? x[3] : c[1];
        p0.w[2] = hiHalf ? c[2] : x[0];  p0.w[3] = hiHalf ? c[3] : x[1];
        p1.w[0] = hiHalf ? x[6] : c[4];  p1.w[1] = hiHalf ? x[7] : c[5];
        p1.w[2] = hiHalf ? c[6] : x[4];  p1.w[3] = hiHalf ? c[7] : x[5];
        // ---- PV: O^T[d][q] += V^T-frag @ P-frag (k = s = st*32 + 16j)
#pragma unroll
        for (int dt = 0; dt < 2; ++dt) {
            bf16x8 v0 = *(const bf16x8*)(Vp + dt * 8192 + st * 32);
            bf16x8 v1 = *(const bf16x8*)(Vp + dt * 8192 + st * 32 + 16);
            oacc[dt] = __builtin_amdgcn_mfma_f32_32x32x16_bf16(v0, p0.v, oacc[dt], 0, 0, 0);
            oacc[dt] = __builtin_amdgcn_mfma_f32_32x32x16_bf16(v1, p1.v, oacc[dt], 0, 0, 0);
        }
    }

    sum_run += __shfl_xor(sum_run, 32);
    float inv = 1.f / sum_run;

    // ---- epilogue: normalize, transpose via per-wave swizzled LDS, store
    u16* ow = lds + wave * 2048;  // 4KB/wave: [q 32][d 64] bf16, XOR-swizzled
    {
        const int q = l31;
#pragma unroll
        for (int dt = 0; dt < 2; ++dt)
#pragma unroll
            for (int rq = 0; rq < 4; ++rq) {
                int d = dt * 32 + rq * 8 + 4 * lh;
                u32 w0 = pk2(oacc[dt][rq * 4 + 0] * inv, oacc[dt][rq * 4 + 1] * inv);
                u32 w1 = pk2(oacc[dt][rq * 4 + 2] * inv, oacc[dt][rq * 4 + 3] * inv);
                int byte = q * 128 + ((d * 2) ^ ((q & 7) << 4));
                *(u32*)((char*)ow + byte) = w0;
                *(u32*)((char*)ow + byte + 4) = w1;
            }
    }
#pragma unroll
    for (int i = 0; i < 4; ++i) {
        int qq = (lane >> 3) + i * 8;
        int byte = qq * 128 + (((lane & 7) * 16) ^ ((qq & 7) << 4));
        bf16x8 val = *(const bf16x8*)((char*)ow + byte);
        *(bf16x8*)(O + (q0 + qq) * 512 + h * 64 + (lane & 7) * 8) = val;
    }
}

// ---------------------------------------------------------------------------
// GroupNorm stats: one block per (b,g); 4096x16 f32 reduction -> per-chan a,d
// ---------------------------------------------------------------------------
__global__ __launch_bounds__(256)
void gn_stats(const float* __restrict__ x, const float* __restrict__ gscale,
              const float* __restrict__ gbias, float* __restrict__ coefA,
              float* __restrict__ coefD)
{
    const int b = blockIdx.x >> 5, g = blockIdx.x & 31;
    const float* base = x + (long)b * 4096 * 512 + g * 16;
    const int tid = threadIdx.x;
    const int p0 = tid >> 2, c0 = (tid & 3) * 4;
    const float* tp = base + (long)p0 * 512 + c0;
    float sum = 0.f, sq = 0.f;
    for (int it = 0; it < 64; ++it) {
        float4 v = *(const float4*)(tp + (long)it * 64 * 512);
        sum += v.x + v.y + v.z + v.w;
        sq += v.x * v.x + v.y * v.y + v.z * v.z + v.w * v.w;
    }
#pragma unroll
    for (int off = 32; off; off >>= 1) {
        sum += __shfl_down(sum, off);
        sq  += __shfl_down(sq, off);
    }
    __shared__ float ssum[4], ssq[4];
    if ((tid & 63) == 0) { ssum[tid >> 6] = sum; ssq[tid >> 6] = sq; }
    __syncthreads();
    if (tid < 16) {
        float S = ssum[0] + ssum[1] + ssum[2] + ssum[3];
        float Q = ssq[0] + ssq[1] + ssq[2] + ssq[3];
        float mean = S * (1.f / 65536.f);
        float var = Q * (1.f / 65536.f) - mean * mean;
        float rstd = rsqrtf(var + 1e-5f);
        int c = g * 16 + tid;
        float a = gscale[c] * rstd;
        coefA[b * 512 + c] = a;
        coefD[b * 512 + c] = gbias[c] - mean * a;
    }
}

// apply GN affine, f32 -> bf16
__global__ __launch_bounds__(256)
void gn_apply(const float* __restrict__ x, const float* __restrict__ coefA,
              const float* __restrict__ coefD, u16* __restrict__ xn)
{
    long e = ((long)blockIdx.x * 256 + threadIdx.x) * 8;
    int b = (int)(e >> 21);
    int c = (int)(e & 511);
    float4 v0 = *(const float4*)(x + e);
    float4 v1 = *(const float4*)(x + e + 4);
    const float* pa = coefA + b * 512 + c;
    const float* pd = coefD + b * 512 + c;
    float f[8] = { v0.x, v0.y, v0.z, v0.w, v1.x, v1.y, v1.z, v1.w };
    u32x4 o;
#pragma unroll
    for (int q = 0; q < 4; ++q) {
        float g0 = f[q * 2] * pa[q * 2] + pd[q * 2];
        float g1 = f[q * 2 + 1] * pa[q * 2 + 1] + pd[q * 2 + 1];
        o[q] = (u32)f2bf(g0) | ((u32)f2bf(g1) << 16);
    }
    *(u32x4*)(xn + e) = o;
}

// f32 -> bf16 bulk convert (n multiple of 8*256)
__global__ __launch_bounds__(256)
void conv_bf16(const float* __restrict__ in, u16* __restrict__ out)
{
    long e = ((long)blockIdx.x * 256 + threadIdx.x) * 8;
    float4 v0 = *(const float4*)(in + e);
    float4 v1 = *(const float4*)(in + e + 4);
    float f[8] = { v0.x, v0.y, v0.z, v0.w, v1.x, v1.y, v1.z, v1.w };
    u32x4 o;
#pragma unroll
    for (int q = 0; q < 4; ++q)
        o[q] = (u32)f2bf(f[q * 2]) | ((u32)f2bf(f[q * 2 + 1]) << 16);
    *(u32x4*)(out + e) = o;
}

// 2D transpose f32 -> bf16 for weights (R,C multiples of 32)
__global__ __launch_bounds__(256)
void transpose_k(const float* __restrict__ in, u16* __restrict__ out, int R, int C)
{
    __shared__ u16 t[32][33];
    int tx = threadIdx.x & 31, ty = threadIdx.x >> 5;
    int r0 = blockIdx.y * 32, c0 = blockIdx.x * 32;
    for (int i = ty; i < 32; i += 8) t[i][tx] = f2bf(in[(long)(r0 + i) * C + c0 + tx]);
    __syncthreads();
    for (int i = ty; i < 32; i += 8) out[(long)(c0 + i) * R + r0 + tx] = t[tx][i];
}

extern "C" void kernel_launch(void* const* d_in, const int* in_sizes, int n_in,
                              void* d_out, int out_size, void* d_ws, size_t ws_size,
                              hipStream_t stream)
{
    const float* x    = (const float*)d_in[0];
    const float* cond = (const float*)d_in[1];
    const float* gsc  = (const float*)d_in[2];
    const float* gbi  = (const float*)d_in[3];
    const float* Wq   = (const float*)d_in[4];
    const float* Wk   = (const float*)d_in[5];
    const float* Wv   = (const float*)d_in[6];
    const float* Wo   = (const float*)d_in[7];
    const float* bo   = (const float*)d_in[8];

    char* ws = (char*)d_ws;
    size_t off = 0;
    auto alloc = [&](size_t bytes) -> void* {
        void* p = ws + off; off += (bytes + 255) & ~(size_t)255; return p;
    };
    u16* WqT   = (u16*)alloc(512 * 512 * 2);
    u16* WkT   = (u16*)alloc(512 * 768 * 2);
    u16* WvT   = (u16*)alloc(512 * 768 * 2);
    u16* WoT   = (u16*)alloc(512 * 512 * 2);
    float* cfA = (float*)alloc(8 * 512 * 4);
    float* cfD = (float*)alloc(8 * 512 * 4);
    u16* condb = (u16*)alloc(2048l * 768 * 2);
    u16* xn    = (u16*)alloc(33554432);   // reused as attention output O
    u16* Qb    = (u16*)alloc(33554432);
    u16* Kb    = (u16*)alloc(2048l * 512 * 2);
    u16* Vt    = (u16*)alloc(2097152);
    u16* Ob = xn;

    transpose_k<<<dim3(16, 16), 256, 0, stream>>>(Wq, WqT, 512, 512);
    transpose_k<<<dim3(16, 24), 256, 0, stream>>>(Wk, WkT, 768, 512);
    transpose_k<<<dim3(16, 24), 256, 0, stream>>>(Wv, WvT, 768, 512);
    transpose_k<<<dim3(16, 16), 256, 0, stream>>>(Wo, WoT, 512, 512);
    conv_bf16<<<768, 256, 0, stream>>>(cond, condb);

    gn_stats<<<256, 256, 0, stream>>>(x, gsc, gbi, cfA, cfD);
    gn_apply<<<8192, 256, 0, stream>>>(x, cfA, cfD, xn);

    // Q = (xn @ WqT) * 0.125*log2(e)  (scores in log2 domain for exp2 softmax)
    gemm_bt<128, 0, false, false><<<dim3(256, 4, 1), 256, 0, stream>>>(
        xn, WqT, Qb, nullptr, nullptr, 512, 512, 512, 512,
        0, 0, 0, 0, 0, 0, 0.18033688011112042f);
    // K = cond @ WkT      (2048 x 512 x 768)
    gemm_bt<128, 0, false, false><<<dim3(16, 4, 1), 256, 0, stream>>>(
        condb, WkT, Kb, nullptr, nullptr, 768, 768, 768, 512,
        0, 0, 0, 0, 0, 0, 1.f);
    // V = cond @ WvT, stored transposed per head -> Vt[b*8+h][64][256]
    gemm_bt<128, 2, false, false><<<dim3(16, 4, 1), 256, 0, stream>>>(
        condb, WvT, Vt, nullptr, nullptr, 768, 768, 768, 0,
        0, 0, 0, 0, 0, 0, 1.f);

    // fused attention: scores+softmax+PV, writes Ob
    attn_fused<<<dim3(32, 64), 256, 0, stream>>>(Qb, Kb, Vt, Ob);

    // out = x + O @ WoT + bo    (32768 x 512 x 512), f32 output
    gemm_bt<128, 1, true, true><<<dim3(256, 4, 1), 256, 0, stream>>>(
        Ob, WoT, d_out, bo, x, 512, 512, 512, 512,
        0, 0, 0, 0, 0, 0, 1.f);
}

// Round 5
// 199.968 us; speedup vs baseline: 1.1960x; 1.1960x over previous
//
#include <hip/hip_runtime.h>
#include <hip/hip_bf16.h>

typedef unsigned short u16;
typedef unsigned int u32;
typedef __attribute__((ext_vector_type(8))) __bf16 bf16x8;
typedef __attribute__((ext_vector_type(4))) float f32x4;
typedef __attribute__((ext_vector_type(16))) float f32x16;
typedef __attribute__((ext_vector_type(4))) u32 u32x4;

#define DEVFN static __device__ __forceinline__

DEVFN float bf2f(u16 v) { union { u32 u; float f; } x; x.u = (u32)v << 16; return x.f; }
DEVFN u16 f2bf(float f) {
    union { float f; u32 u; } x; x.f = f;
    u32 r = x.u + 0x7fff + ((x.u >> 16) & 1);
    return (u16)(r >> 16);
}

union BF2 { struct { __bf16 lo, hi; } s; u32 w; };
DEVFN u32 pk2(float a, float b) { BF2 t; t.s.lo = (__bf16)a; t.s.hi = (__bf16)b; return t.w; }

DEVFN void gload_lds16(const u16* g, u16* l) {
    __builtin_amdgcn_global_load_lds((const __attribute__((address_space(1))) u32*)g,
                                     (__attribute__((address_space(3))) u32*)l, 16, 0, 0);
}

// ---------------------------------------------------------------------------
// Generic C = A (M,K) @ B^T (N,K), bf16 in, f32 accum.
// OUTMODE: 0 = bf16 C; 1 = f32 C (+opt f32 bias/residual); 2 = bf16 Vt store
// ---------------------------------------------------------------------------
template<int BN, int OUTMODE, bool BIAS, bool RES>
__global__ __launch_bounds__(256)
void gemm_bt(const u16* __restrict__ A, const u16* __restrict__ B,
             void* __restrict__ Cv, const float* __restrict__ bias,
             const float* __restrict__ res,
             int K, int lda, int ldb, int ldc,
             long sAb, long sAh, long sBb, long sBh, long sCb, long sCh,
             float scale)
{
    constexpr int NF = BN / 32;  // n-frags per wave
    __shared__ u16 smem[4096 + BN * 32];
    const int tid = threadIdx.x;
    const int lane = tid & 63, wave = tid >> 6;
    const int wr = wave >> 1, wc = wave & 1;
    const int z = blockIdx.z, zb = z >> 3, zh = z & 7;

    const u16* Ab = A + zb * sAb + zh * sAh + (long)blockIdx.x * 128 * lda;
    const u16* Bb = B + zb * sBb + zh * sBh + (long)blockIdx.y * BN * ldb;

    const int ra = tid >> 2, ca = (tid & 3) * 8;
    const u16* pA0 = Ab + (long)ra * lda + ca;
    const u16* pA1 = Ab + (long)(ra + 64) * lda + ca;
    u16* lA0 = smem + tid * 8;
    u16* lA1 = smem + (256 + tid) * 8;
    const u16* pB0 = Bb + (long)ra * ldb + ca;
    const u16* pB1 = Bb + (long)(ra + 64) * ldb + ca;
    u16* lB0 = smem + 4096 + tid * 8;
    u16* lB1 = smem + 4096 + (256 + tid) * 8;

    const int foff = ((lane & 15) * 4 + (lane >> 4)) * 8;  // frag offset (u16)
    const u16* aF = smem + wr * 2048 + foff;
    const u16* bF = smem + 4096 + wc * (NF * 512) + foff;

    f32x4 acc[4][NF];
#pragma unroll
    for (int i = 0; i < 4; ++i)
#pragma unroll
        for (int j = 0; j < NF; ++j) acc[i][j] = (f32x4){0.f, 0.f, 0.f, 0.f};

    for (int k0 = 0; k0 < K; k0 += 32) {
        gload_lds16(pA0 + k0, lA0);
        gload_lds16(pA1 + k0, lA1);
        gload_lds16(pB0 + k0, lB0);
        if constexpr (BN == 128) gload_lds16(pB1 + k0, lB1);
        asm volatile("s_waitcnt vmcnt(0)" ::: "memory");
        __syncthreads();
        bf16x8 av[4], bv[NF];
#pragma unroll
        for (int i = 0; i < 4; ++i) av[i] = *(const bf16x8*)(aF + i * 512);
#pragma unroll
        for (int j = 0; j < NF; ++j) bv[j] = *(const bf16x8*)(bF + j * 512);
#pragma unroll
        for (int i = 0; i < 4; ++i)
#pragma unroll
            for (int j = 0; j < NF; ++j)
                acc[i][j] = __builtin_amdgcn_mfma_f32_16x16x32_bf16(av[i], bv[j], acc[i][j], 0, 0, 0);
        __syncthreads();
    }

    const int m0 = blockIdx.x * 128 + wr * 64 + (lane >> 4) * 4;
    const int n0 = blockIdx.y * BN + wc * (BN / 2) + (lane & 15);
    if constexpr (OUTMODE == 0) {
        u16* Cb = (u16*)Cv + zb * sCb + zh * sCh;
#pragma unroll
        for (int i = 0; i < 4; ++i)
#pragma unroll
            for (int j = 0; j < NF; ++j) {
                int n = n0 + j * 16;
#pragma unroll
                for (int r = 0; r < 4; ++r) {
                    int m = m0 + i * 16 + r;
                    Cb[(long)m * ldc + n] = f2bf(acc[i][j][r] * scale);
                }
            }
    } else if constexpr (OUTMODE == 1) {
        float* Cb = (float*)Cv + zb * sCb + zh * sCh;
#pragma unroll
        for (int i = 0; i < 4; ++i)
#pragma unroll
            for (int j = 0; j < NF; ++j) {
                int n = n0 + j * 16;
                float bv_ = BIAS ? bias[n] : 0.f;
#pragma unroll
                for (int r = 0; r < 4; ++r) {
                    int m = m0 + i * 16 + r;
                    float v = acc[i][j][r] * scale + bv_;
                    if constexpr (RES) v += res[(long)m * ldc + n];
                    Cb[(long)m * ldc + n] = v;
                }
            }
    } else {
        // store V transposed: Vt[(b*8+h)][d][s]; m=b*256+s, n=h*64+d
#pragma unroll
        for (int i = 0; i < 4; ++i) {
            int m = m0 + i * 16;
            int b = m >> 8, s = m & 255;
#pragma unroll
            for (int j = 0; j < NF; ++j) {
                int n = n0 + j * 16;
                int h = n >> 6, d = n & 63;
                ushort4 pk;
                pk.x = f2bf(acc[i][j][0]); pk.y = f2bf(acc[i][j][1]);
                pk.z = f2bf(acc[i][j][2]); pk.w = f2bf(acc[i][j][3]);
                *(ushort4*)((u16*)Cv + (((long)(b * 8 + h) * 64 + d) * 256 + s)) = pk;
            }
        }
    }
}

// ---------------------------------------------------------------------------
// Fused attention v3: LDS-staged K/V (coalesced, frag-linear, R3-verified
// mapping) + online softmax (register-light, R4-verified math/mapping).
// grid (16 qchunks, 64 bh), 512 threads = 8 waves x 32 queries.
// One barrier after staging; waves then run independently (K/V read-only).
// LDS: K frags 32KB | V frags 32KB | epilogue scratch 16KB (2 shifts) = 80KB
// -> 2 blocks/CU, 4 waves/SIMD. Q pre-scaled by 0.125*log2e (exp2 domain).
// ---------------------------------------------------------------------------
union U8 { u32 w[4]; bf16x8 v; };

__global__ __launch_bounds__(512, 4)
void attn_fused(const u16* __restrict__ Q, const u16* __restrict__ K,
                const u16* __restrict__ Vt, u16* __restrict__ O)
{
    __shared__ u16 lds[40960];  // 80KB
    const int tid = threadIdx.x, lane = tid & 63, wave = tid >> 6;
    const int bh = blockIdx.y, b = bh >> 3, h = bh & 7;
    const int l31 = lane & 31, lh = lane >> 5;
    const long q0 = (long)b * 4096 + blockIdx.x * 256 + wave * 32;
    const bool hiHalf = (lh != 0);

    // ---- stage K/V frag-linear (each wave stages one frag per iteration)
    {
        const u16* Kb_ = K + (long)b * 256 * 512 + h * 64;
        const u16* Vb_ = Vt + (long)bh * 16384;
#pragma unroll
        for (int it = 0; it < 4; ++it) {
            int f = it * 8 + wave;           // 0..31
            int st = f >> 2, kc = f & 3;
            gload_lds16(Kb_ + (long)(st * 32 + l31) * 512 + kc * 16 + lh * 8,
                        lds + f * 512 + lane * 8);
            int dt = f >> 4, ks = f & 15;
            gload_lds16(Vb_ + (long)(dt * 32 + l31) * 256 + ks * 16 + lh * 8,
                        lds + 16384 + f * 512 + lane * 8);
        }
    }
    // Q B-frags (col=q=lane&31, k=kc*16+lh*8+j), loaded once, global->reg
    bf16x8 qf[4];
    {
        const u16* Qp = Q + (q0 + l31) * 512 + h * 64 + lh * 8;
#pragma unroll
        for (int kc = 0; kc < 4; ++kc) qf[kc] = *(const bf16x8*)(Qp + kc * 16);
    }
    asm volatile("s_waitcnt vmcnt(0)" ::: "memory");
    __syncthreads();

    f32x16 oacc[2];
#pragma unroll
    for (int dt = 0; dt < 2; ++dt)
#pragma unroll
        for (int r = 0; r < 16; ++r) oacc[dt][r] = 0.f;
    float m_run = -3e38f, sum_run = 0.f;

#pragma unroll
    for (int st = 0; st < 8; ++st) {
        // ---- QK^T tile: S^T[s][q], C row=(r&3)+8*(r>>2)+4*lh, col=l31
        f32x16 sc;
#pragma unroll
        for (int r = 0; r < 16; ++r) sc[r] = 0.f;
        __builtin_amdgcn_s_setprio(1);
#pragma unroll
        for (int kc = 0; kc < 4; ++kc) {
            bf16x8 af = *(const bf16x8*)(lds + (st * 4 + kc) * 512 + lane * 8);
            sc = __builtin_amdgcn_mfma_f32_32x32x16_bf16(af, qf[kc], sc, 0, 0, 0);
        }
        __builtin_amdgcn_s_setprio(0);
        // ---- tile max (in-lane 16 + pair lane^32)
        float tm = sc[0];
#pragma unroll
        for (int r = 1; r < 16; ++r) tm = fmaxf(tm, sc[r]);
        tm = fmaxf(tm, __shfl_xor(tm, 32));
        // ---- defer-max: rescale only when tile max grew past THR=8 (log2)
        if (!__all(tm <= m_run + 8.f)) {
            float mnew = fmaxf(m_run, tm);
            float fac = exp2f(m_run - mnew);
            m_run = mnew;
            sum_run *= fac;
#pragma unroll
            for (int dt = 0; dt < 2; ++dt)
#pragma unroll
                for (int r = 0; r < 16; ++r) oacc[dt][r] *= fac;
        }
        // ---- P = exp2(S' - m), in place
#pragma unroll
        for (int r = 0; r < 16; ++r) {
            float e = exp2f(sc[r] - m_run);
            sc[r] = e; sum_run += e;
        }
        // ---- pack to bf16 pairs + half-swap (R3/R4-validated mapping)
        u32 c[8], x[8];
#pragma unroll
        for (int i = 0; i < 8; ++i) c[i] = pk2(sc[2 * i], sc[2 * i + 1]);
#pragma unroll
        for (int i = 0; i < 8; ++i) x[i] = (u32)__shfl_xor((int)c[i], 32);
        U8 p0, p1;
        p0.w[0] = hiHalf ? x[2] : c[0];  p0.w[1] = hiHalf ? x[3] : c[1];
        p0.w[2] = hiHalf ? c[2] : x[0];  p0.w[3] = hiHalf ? c[3] : x[1];
        p1.w[0] = hiHalf ? x[6] : c[4];  p1.w[1] = hiHalf ? x[7] : c[5];
        p1.w[2] = hiHalf ? c[6] : x[4];  p1.w[3] = hiHalf ? c[7] : x[5];
        // ---- PV: O^T[d][q] += V^T-frag @ P-frag (k = s = st*32 + 16j)
        __builtin_amdgcn_s_setprio(1);
#pragma unroll
        for (int dt = 0; dt < 2; ++dt) {
            bf16x8 v0 = *(const bf16x8*)(lds + 16384 + (dt * 16 + st * 2) * 512 + lane * 8);
            bf16x8 v1 = *(const bf16x8*)(lds + 16384 + (dt * 16 + st * 2 + 1) * 512 + lane * 8);
            oacc[dt] = __builtin_amdgcn_mfma_f32_32x32x16_bf16(v0, p0.v, oacc[dt], 0, 0, 0);
            oacc[dt] = __builtin_amdgcn_mfma_f32_32x32x16_bf16(v1, p1.v, oacc[dt], 0, 0, 0);
        }
        __builtin_amdgcn_s_setprio(0);
    }

    sum_run += __shfl_xor(sum_run, 32);
    float inv = 1.f / sum_run;

    // ---- epilogue: normalize, transpose via swizzled LDS scratch (2 shifts)
    u16* ow = lds + 32768 + (wave & 3) * 2048;  // 4KB per wave
    const int shift = wave >> 2;                // 0: waves 0-3, 1: waves 4-7
#pragma unroll
    for (int s_ = 0; s_ < 2; ++s_) {
        if (s_ == 1) __syncthreads();
        if (shift == s_) {
            const int q = l31;
#pragma unroll
            for (int dt = 0; dt < 2; ++dt)
#pragma unroll
                for (int rq = 0; rq < 4; ++rq) {
                    int d = dt * 32 + rq * 8 + 4 * lh;
                    u32 w0 = pk2(oacc[dt][rq * 4 + 0] * inv, oacc[dt][rq * 4 + 1] * inv);
                    u32 w1 = pk2(oacc[dt][rq * 4 + 2] * inv, oacc[dt][rq * 4 + 3] * inv);
                    int byte = q * 128 + ((d * 2) ^ ((q & 7) << 4));
                    *(u32*)((char*)ow + byte) = w0;
                    *(u32*)((char*)ow + byte + 4) = w1;
                }
#pragma unroll
            for (int i = 0; i < 4; ++i) {
                int qq = (lane >> 3) + i * 8;
                int byte = qq * 128 + (((lane & 7) * 16) ^ ((qq & 7) << 4));
                bf16x8 val = *(const bf16x8*)((char*)ow + byte);
                *(bf16x8*)(O + (q0 + qq) * 512 + h * 64 + (lane & 7) * 8) = val;
            }
        }
    }
}

// ---------------------------------------------------------------------------
// GroupNorm stats: one block per (b,g); 4096x16 f32 reduction -> per-chan a,d
// ---------------------------------------------------------------------------
__global__ __launch_bounds__(256)
void gn_stats(const float* __restrict__ x, const float* __restrict__ gscale,
              const float* __restrict__ gbias, float* __restrict__ coefA,
              float* __restrict__ coefD)
{
    const int b = blockIdx.x >> 5, g = blockIdx.x & 31;
    const float* base = x + (long)b * 4096 * 512 + g * 16;
    const int tid = threadIdx.x;
    const int p0 = tid >> 2, c0 = (tid & 3) * 4;
    const float* tp = base + (long)p0 * 512 + c0;
    float sum = 0.f, sq = 0.f;
    for (int it = 0; it < 64; ++it) {
        float4 v = *(const float4*)(tp + (long)it * 64 * 512);
        sum += v.x + v.y + v.z + v.w;
        sq += v.x * v.x + v.y * v.y + v.z * v.z + v.w * v.w;
    }
#pragma unroll
    for (int off = 32; off; off >>= 1) {
        sum += __shfl_down(sum, off);
        sq  += __shfl_down(sq, off);
    }
    __shared__ float ssum[4], ssq[4];
    if ((tid & 63) == 0) { ssum[tid >> 6] = sum; ssq[tid >> 6] = sq; }
    __syncthreads();
    if (tid < 16) {
        float S = ssum[0] + ssum[1] + ssum[2] + ssum[3];
        float Q = ssq[0] + ssq[1] + ssq[2] + ssq[3];
        float mean = S * (1.f / 65536.f);
        float var = Q * (1.f / 65536.f) - mean * mean;
        float rstd = rsqrtf(var + 1e-5f);
        int c = g * 16 + tid;
        float a = gscale[c] * rstd;
        coefA[b * 512 + c] = a;
        coefD[b * 512 + c] = gbias[c] - mean * a;
    }
}

// apply GN affine, f32 -> bf16 (grid-stride)
__global__ __launch_bounds__(256)
void gn_apply(const float* __restrict__ x, const float* __restrict__ coefA,
              const float* __restrict__ coefD, u16* __restrict__ xn, int nvec)
{
    for (long v8 = blockIdx.x * 256 + threadIdx.x; v8 < nvec; v8 += (long)gridDim.x * 256) {
        long e = v8 * 8;
        int b = (int)(e >> 21);
        int c = (int)(e & 511);
        float4 v0 = *(const float4*)(x + e);
        float4 v1 = *(const float4*)(x + e + 4);
        const float* pa = coefA + b * 512 + c;
        const float* pd = coefD + b * 512 + c;
        float f[8] = { v0.x, v0.y, v0.z, v0.w, v1.x, v1.y, v1.z, v1.w };
        u32x4 o;
#pragma unroll
        for (int q = 0; q < 4; ++q) {
            float g0 = f[q * 2] * pa[q * 2] + pd[q * 2];
            float g1 = f[q * 2 + 1] * pa[q * 2 + 1] + pd[q * 2 + 1];
            o[q] = (u32)f2bf(g0) | ((u32)f2bf(g1) << 16);
        }
        *(u32x4*)(xn + e) = o;
    }
}

// f32 -> bf16 bulk convert (n multiple of 8*256)
__global__ __launch_bounds__(256)
void conv_bf16(const float* __restrict__ in, u16* __restrict__ out)
{
    long e = ((long)blockIdx.x * 256 + threadIdx.x) * 8;
    float4 v0 = *(const float4*)(in + e);
    float4 v1 = *(const float4*)(in + e + 4);
    float f[8] = { v0.x, v0.y, v0.z, v0.w, v1.x, v1.y, v1.z, v1.w };
    u32x4 o;
#pragma unroll
    for (int q = 0; q < 4; ++q)
        o[q] = (u32)f2bf(f[q * 2]) | ((u32)f2bf(f[q * 2 + 1]) << 16);
    *(u32x4*)(out + e) = o;
}

// all 4 weight transposes in one launch: z selects matrix (f32 -> bf16)
__global__ __launch_bounds__(256)
void transpose_all(const float* __restrict__ Wq, const float* __restrict__ Wk,
                   const float* __restrict__ Wv, const float* __restrict__ Wo,
                   u16* __restrict__ WqT, u16* __restrict__ WkT,
                   u16* __restrict__ WvT, u16* __restrict__ WoT)
{
    __shared__ u16 t[32][33];
    const int z = blockIdx.z;
    const float* in = (z == 0) ? Wq : (z == 1) ? Wk : (z == 2) ? Wv : Wo;
    u16* out = (z == 0) ? WqT : (z == 1) ? WkT : (z == 2) ? WvT : WoT;
    const int R = (z == 1 || z == 2) ? 768 : 512, C = 512;
    const int r0 = blockIdx.y * 32, c0 = blockIdx.x * 32;
    if (r0 >= R) return;
    int tx = threadIdx.x & 31, ty = threadIdx.x >> 5;
    for (int i = ty; i < 32; i += 8) t[i][tx] = f2bf(in[(long)(r0 + i) * C + c0 + tx]);
    __syncthreads();
    for (int i = ty; i < 32; i += 8) out[(long)(c0 + i) * R + r0 + tx] = t[tx][i];
}

extern "C" void kernel_launch(void* const* d_in, const int* in_sizes, int n_in,
                              void* d_out, int out_size, void* d_ws, size_t ws_size,
                              hipStream_t stream)
{
    const float* x    = (const float*)d_in[0];
    const float* cond = (const float*)d_in[1];
    const float* gsc  = (const float*)d_in[2];
    const float* gbi  = (const float*)d_in[3];
    const float* Wq   = (const float*)d_in[4];
    const float* Wk   = (const float*)d_in[5];
    const float* Wv   = (const float*)d_in[6];
    const float* Wo   = (const float*)d_in[7];
    const float* bo   = (const float*)d_in[8];

    char* ws = (char*)d_ws;
    size_t off = 0;
    auto alloc = [&](size_t bytes) -> void* {
        void* p = ws + off; off += (bytes + 255) & ~(size_t)255; return p;
    };
    u16* WqT   = (u16*)alloc(512 * 512 * 2);
    u16* WkT   = (u16*)alloc(512 * 768 * 2);
    u16* WvT   = (u16*)alloc(512 * 768 * 2);
    u16* WoT   = (u16*)alloc(512 * 512 * 2);
    float* cfA = (float*)alloc(8 * 512 * 4);
    float* cfD = (float*)alloc(8 * 512 * 4);
    u16* condb = (u16*)alloc(2048l * 768 * 2);
    u16* xn    = (u16*)alloc(33554432);   // reused as attention output O
    u16* Qb    = (u16*)alloc(33554432);
    u16* Kb    = (u16*)alloc(2048l * 512 * 2);
    u16* Vt    = (u16*)alloc(2097152);
    u16* Ob = xn;

    transpose_all<<<dim3(16, 24, 4), 256, 0, stream>>>(Wq, Wk, Wv, Wo, WqT, WkT, WvT, WoT);
    conv_bf16<<<768, 256, 0, stream>>>(cond, condb);

    gn_stats<<<256, 256, 0, stream>>>(x, gsc, gbi, cfA, cfD);
    gn_apply<<<2048, 256, 0, stream>>>(x, cfA, cfD, xn, 2097152);

    // Q = (xn @ WqT) * 0.125*log2(e)  (scores in log2 domain for exp2 softmax)
    gemm_bt<128, 0, false, false><<<dim3(256, 4, 1), 256, 0, stream>>>(
        xn, WqT, Qb, nullptr, nullptr, 512, 512, 512, 512,
        0, 0, 0, 0, 0, 0, 0.18033688011112042f);
    // K = cond @ WkT      (2048 x 512 x 768)
    gemm_bt<128, 0, false, false><<<dim3(16, 4, 1), 256, 0, stream>>>(
        condb, WkT, Kb, nullptr, nullptr, 768, 768, 768, 512,
        0, 0, 0, 0, 0, 0, 1.f);
    // V = cond @ WvT, stored transposed per head -> Vt[b*8+h][64][256]
    gemm_bt<128, 2, false, false><<<dim3(16, 4, 1), 256, 0, stream>>>(
        condb, WvT, Vt, nullptr, nullptr, 768, 768, 768, 0,
        0, 0, 0, 0, 0, 0, 1.f);

    // fused attention: scores+softmax+PV, writes Ob
    attn_fused<<<dim3(16, 64), 512, 0, stream>>>(Qb, Kb, Vt, Ob);

    // out = x + O @ WoT + bo    (32768 x 512 x 512), f32 output
    gemm_bt<128, 1, true, true><<<dim3(256, 4, 1), 256, 0, stream>>>(
        Ob, WoT, d_out, bo, x, 512, 512, 512, 512,
        0, 0, 0, 0, 0, 0, 1.f);
}

// Round 6
// 195.372 us; speedup vs baseline: 1.2242x; 1.0235x over previous
//
#include <hip/hip_runtime.h>
#include <hip/hip_bf16.h>

typedef unsigned short u16;
typedef unsigned int u32;
typedef __attribute__((ext_vector_type(8))) __bf16 bf16x8;
typedef __attribute__((ext_vector_type(4))) float f32x4;
typedef __attribute__((ext_vector_type(16))) float f32x16;
typedef __attribute__((ext_vector_type(4))) u32 u32x4;

#define DEVFN static __device__ __forceinline__

DEVFN float bf2f(u16 v) { union { u32 u; float f; } x; x.u = (u32)v << 16; return x.f; }
DEVFN u16 f2bf(float f) {
    union { float f; u32 u; } x; x.f = f;
    u32 r = x.u + 0x7fff + ((x.u >> 16) & 1);
    return (u16)(r >> 16);
}

union BF2 { struct { __bf16 lo, hi; } s; u32 w; };
DEVFN u32 pk2(float a, float b) { BF2 t; t.s.lo = (__bf16)a; t.s.hi = (__bf16)b; return t.w; }

DEVFN void gload_lds16(const u16* g, u16* l) {
    __builtin_amdgcn_global_load_lds((const __attribute__((address_space(1))) u32*)g,
                                     (__attribute__((address_space(3))) u32*)l, 16, 0, 0);
}

// ---------------------------------------------------------------------------
// C = A (M,K) @ B^T (N,K), bf16 MFMA, f32 accum. Tile 128x128, BK=64,
// 4 waves 2x2, wave tile 64x64 (4x4 16x16x32 frags, 2 k-chunks per stage).
// LDS frag-linear per k-chunk: slot g (8 u16) -> kk=g>>9, fr=(g>>6)&7, l=g&63,
// row=fr*16+(l>>2), ch=kk*32+(l&3)*8.  Staging pass p: g=p*256+tid.
// OUTMODE: 0 = bf16 C (scaled); 1 = f32 C via coalesced LDS epilogue
// (+bias/residual); 2 = bf16 Vt store.  AFF: A is f32, GN affine applied
// during staging (coefA/coefD per (m>>12)*512+channel), packed to bf16.
// ---------------------------------------------------------------------------
template<int OUTMODE, bool BIAS, bool RES, bool AFF>
__global__ __launch_bounds__(256)
void gemm_bt(const void* __restrict__ Av, const u16* __restrict__ B,
             void* __restrict__ Cv, const float* __restrict__ bias,
             const float* __restrict__ res,
             const float* __restrict__ cfA, const float* __restrict__ cfD,
             int K, int lda, int ldb, int ldc, float scale)
{
    __shared__ u16 smem[16384];  // A 8192 u16 | B 8192 u16 (32 KB)
    const int tid = threadIdx.x;
    const int lane = tid & 63, wave = tid >> 6;
    const int wr = wave >> 1, wc = wave & 1;

    const u16* Bb = B + (long)blockIdx.y * 128 * ldb;
    const int foff = ((lane & 15) * 4 + (lane >> 4)) * 8;  // u16 units

    f32x4 acc[4][4];
#pragma unroll
    for (int i = 0; i < 4; ++i)
#pragma unroll
        for (int j = 0; j < 4; ++j) acc[i][j] = (f32x4){0.f, 0.f, 0.f, 0.f};

    for (int k0 = 0; k0 < K; k0 += 64) {
        // ---- stage B (global_load_lds, 4 passes)
#pragma unroll
        for (int p = 0; p < 4; ++p) {
            int row = ((p & 1) * 4 + (tid >> 6)) * 16 + ((tid & 63) >> 2);
            int chl = (p >> 1) * 32 + (tid & 3) * 8;
            gload_lds16(Bb + (long)row * ldb + k0 + chl,
                        smem + 8192 + (p * 256 + tid) * 8);
        }
        // ---- stage A
        if constexpr (AFF) {
            const float* xf = (const float*)Av;
#pragma unroll
            for (int p = 0; p < 4; ++p) {
                int row = ((p & 1) * 4 + (tid >> 6)) * 16 + ((tid & 63) >> 2);
                int chl = (p >> 1) * 32 + (tid & 3) * 8;
                long m = (long)blockIdx.x * 128 + row;
                int c = k0 + chl;
                const float* src = xf + m * lda + c;
                float4 v0 = *(const float4*)(src);
                float4 v1 = *(const float4*)(src + 4);
                int cb = (int)((m >> 12) << 9) + c;
                float4 a0 = *(const float4*)(cfA + cb);
                float4 a1 = *(const float4*)(cfA + cb + 4);
                float4 d0 = *(const float4*)(cfD + cb);
                float4 d1 = *(const float4*)(cfD + cb + 4);
                u32x4 o;
                o[0] = pk2(v0.x * a0.x + d0.x, v0.y * a0.y + d0.y);
                o[1] = pk2(v0.z * a0.z + d0.z, v0.w * a0.w + d0.w);
                o[2] = pk2(v1.x * a1.x + d1.x, v1.y * a1.y + d1.y);
                o[3] = pk2(v1.z * a1.z + d1.z, v1.w * a1.w + d1.w);
                *(u32x4*)(smem + (p * 256 + tid) * 8) = o;
            }
        } else {
            const u16* Ab = (const u16*)Av + (long)blockIdx.x * 128 * lda;
#pragma unroll
            for (int p = 0; p < 4; ++p) {
                int row = ((p & 1) * 4 + (tid >> 6)) * 16 + ((tid & 63) >> 2);
                int chl = (p >> 1) * 32 + (tid & 3) * 8;
                gload_lds16(Ab + (long)row * lda + k0 + chl,
                            smem + (p * 256 + tid) * 8);
            }
        }
        asm volatile("s_waitcnt vmcnt(0)" ::: "memory");
        __syncthreads();
        // ---- 2 k-chunks x 16 MFMA
#pragma unroll
        for (int kk = 0; kk < 2; ++kk) {
            bf16x8 av[4], bv[4];
#pragma unroll
            for (int i = 0; i < 4; ++i)
                av[i] = *(const bf16x8*)(smem + kk * 4096 + (wr * 4 + i) * 512 + foff);
#pragma unroll
            for (int j = 0; j < 4; ++j)
                bv[j] = *(const bf16x8*)(smem + 8192 + kk * 4096 + (wc * 4 + j) * 512 + foff);
#pragma unroll
            for (int i = 0; i < 4; ++i)
#pragma unroll
                for (int j = 0; j < 4; ++j)
                    acc[i][j] = __builtin_amdgcn_mfma_f32_16x16x32_bf16(av[i], bv[j], acc[i][j], 0, 0, 0);
        }
        __syncthreads();
    }

    const int m0 = blockIdx.x * 128 + wr * 64 + (lane >> 4) * 4;
    const int n0 = blockIdx.y * 128 + wc * 64 + (lane & 15);
    if constexpr (OUTMODE == 0) {
        u16* Cb = (u16*)Cv;
#pragma unroll
        for (int i = 0; i < 4; ++i)
#pragma unroll
            for (int j = 0; j < 4; ++j) {
                int n = n0 + j * 16;
#pragma unroll
                for (int r = 0; r < 4; ++r) {
                    int m = m0 + i * 16 + r;
                    Cb[(long)m * ldc + n] = f2bf(acc[i][j][r] * scale);
                }
            }
    } else if constexpr (OUTMODE == 1) {
        // coalesced f32 epilogue through padded LDS (32 x 132), 4 row-chunks
        float* cl = (float*)smem;
        float* Co = (float*)Cv;
#pragma unroll
        for (int i = 0; i < 4; ++i) {
            __syncthreads();
#pragma unroll
            for (int j = 0; j < 4; ++j)
#pragma unroll
                for (int r = 0; r < 4; ++r) {
                    int rl = wr * 16 + (lane >> 4) * 4 + r;
                    int col = wc * 64 + j * 16 + (lane & 15);
                    cl[rl * 132 + col] = acc[i][j][r];
                }
            __syncthreads();
            int rl = tid >> 3;
            int c0 = (tid & 7) * 16;
            long m = (long)blockIdx.x * 128 + i * 16 + (rl & 15) + (rl >> 4) * 64;
            long n = (long)blockIdx.y * 128 + c0;
#pragma unroll
            for (int q = 0; q < 4; ++q) {
                float4 v = *(float4*)(cl + rl * 132 + c0 + q * 4);
                float4 o;
                o.x = v.x * scale; o.y = v.y * scale;
                o.z = v.z * scale; o.w = v.w * scale;
                if constexpr (BIAS) {
                    float4 b4 = *(const float4*)(bias + n + q * 4);
                    o.x += b4.x; o.y += b4.y; o.z += b4.z; o.w += b4.w;
                }
                if constexpr (RES) {
                    float4 r4 = *(const float4*)(res + m * ldc + n + q * 4);
                    o.x += r4.x; o.y += r4.y; o.z += r4.z; o.w += r4.w;
                }
                *(float4*)(Co + m * ldc + n + q * 4) = o;
            }
        }
    } else {
        // store V transposed: Vt[(b*8+h)][d][s]; m=b*256+s, n=h*64+d
#pragma unroll
        for (int i = 0; i < 4; ++i) {
            int m = m0 + i * 16;
            int b = m >> 8, s = m & 255;
#pragma unroll
            for (int j = 0; j < 4; ++j) {
                int n = n0 + j * 16;
                int h = n >> 6, d = n & 63;
                ushort4 pk;
                pk.x = f2bf(acc[i][j][0]); pk.y = f2bf(acc[i][j][1]);
                pk.z = f2bf(acc[i][j][2]); pk.w = f2bf(acc[i][j][3]);
                *(ushort4*)((u16*)Cv + (((long)(b * 8 + h) * 64 + d) * 256 + s)) = pk;
            }
        }
    }
}

// ---------------------------------------------------------------------------
// Fused attention v3 (unchanged from R5, verified): LDS-staged K/V + online
// softmax. grid (16, 64), 512 threads = 8 waves x 32 queries.
// ---------------------------------------------------------------------------
union U8 { u32 w[4]; bf16x8 v; };

__global__ __launch_bounds__(512, 4)
void attn_fused(const u16* __restrict__ Q, const u16* __restrict__ K,
                const u16* __restrict__ Vt, u16* __restrict__ O)
{
    __shared__ u16 lds[40960];  // 80KB
    const int tid = threadIdx.x, lane = tid & 63, wave = tid >> 6;
    const int bh = blockIdx.y, b = bh >> 3, h = bh & 7;
    const int l31 = lane & 31, lh = lane >> 5;
    const long q0 = (long)b * 4096 + blockIdx.x * 256 + wave * 32;
    const bool hiHalf = (lh != 0);

    {
        const u16* Kb_ = K + (long)b * 256 * 512 + h * 64;
        const u16* Vb_ = Vt + (long)bh * 16384;
#pragma unroll
        for (int it = 0; it < 4; ++it) {
            int f = it * 8 + wave;           // 0..31
            int st = f >> 2, kc = f & 3;
            gload_lds16(Kb_ + (long)(st * 32 + l31) * 512 + kc * 16 + lh * 8,
                        lds + f * 512 + lane * 8);
            int dt = f >> 4, ks = f & 15;
            gload_lds16(Vb_ + (long)(dt * 32 + l31) * 256 + ks * 16 + lh * 8,
                        lds + 16384 + f * 512 + lane * 8);
        }
    }
    bf16x8 qf[4];
    {
        const u16* Qp = Q + (q0 + l31) * 512 + h * 64 + lh * 8;
#pragma unroll
        for (int kc = 0; kc < 4; ++kc) qf[kc] = *(const bf16x8*)(Qp + kc * 16);
    }
    asm volatile("s_waitcnt vmcnt(0)" ::: "memory");
    __syncthreads();

    f32x16 oacc[2];
#pragma unroll
    for (int dt = 0; dt < 2; ++dt)
#pragma unroll
        for (int r = 0; r < 16; ++r) oacc[dt][r] = 0.f;
    float m_run = -3e38f, sum_run = 0.f;

#pragma unroll
    for (int st = 0; st < 8; ++st) {
        f32x16 sc;
#pragma unroll
        for (int r = 0; r < 16; ++r) sc[r] = 0.f;
        __builtin_amdgcn_s_setprio(1);
#pragma unroll
        for (int kc = 0; kc < 4; ++kc) {
            bf16x8 af = *(const bf16x8*)(lds + (st * 4 + kc) * 512 + lane * 8);
            sc = __builtin_amdgcn_mfma_f32_32x32x16_bf16(af, qf[kc], sc, 0, 0, 0);
        }
        __builtin_amdgcn_s_setprio(0);
        float tm = sc[0];
#pragma unroll
        for (int r = 1; r < 16; ++r) tm = fmaxf(tm, sc[r]);
        tm = fmaxf(tm, __shfl_xor(tm, 32));
        if (!__all(tm <= m_run + 8.f)) {
            float mnew = fmaxf(m_run, tm);
            float fac = exp2f(m_run - mnew);
            m_run = mnew;
            sum_run *= fac;
#pragma unroll
            for (int dt = 0; dt < 2; ++dt)
#pragma unroll
                for (int r = 0; r < 16; ++r) oacc[dt][r] *= fac;
        }
#pragma unroll
        for (int r = 0; r < 16; ++r) {
            float e = exp2f(sc[r] - m_run);
            sc[r] = e; sum_run += e;
        }
        u32 c[8], x[8];
#pragma unroll
        for (int i = 0; i < 8; ++i) c[i] = pk2(sc[2 * i], sc[2 * i + 1]);
#pragma unroll
        for (int i = 0; i < 8; ++i) x[i] = (u32)__shfl_xor((int)c[i], 32);
        U8 p0, p1;
        p0.w[0] = hiHalf ? x[2] : c[0];  p0.w[1] = hiHalf ? x[3] : c[1];
        p0.w[2] = hiHalf ? c[2] : x[0];  p0.w[3] = hiHalf ? c[3] : x[1];
        p1.w[0] = hiHalf ? x[6] : c[4];  p1.w[1] = hiHalf ? x[7] : c[5];
        p1.w[2] = hiHalf ? c[6] : x[4];  p1.w[3] = hiHalf ? c[7] : x[5];
        __builtin_amdgcn_s_setprio(1);
#pragma unroll
        for (int dt = 0; dt < 2; ++dt) {
            bf16x8 v0 = *(const bf16x8*)(lds + 16384 + (dt * 16 + st * 2) * 512 + lane * 8);
            bf16x8 v1 = *(const bf16x8*)(lds + 16384 + (dt * 16 + st * 2 + 1) * 512 + lane * 8);
            oacc[dt] = __builtin_amdgcn_mfma_f32_32x32x16_bf16(v0, p0.v, oacc[dt], 0, 0, 0);
            oacc[dt] = __builtin_amdgcn_mfma_f32_32x32x16_bf16(v1, p1.v, oacc[dt], 0, 0, 0);
        }
        __builtin_amdgcn_s_setprio(0);
    }

    sum_run += __shfl_xor(sum_run, 32);
    float inv = 1.f / sum_run;

    u16* ow = lds + 32768 + (wave & 3) * 2048;
    const int shift = wave >> 2;
#pragma unroll
    for (int s_ = 0; s_ < 2; ++s_) {
        if (s_ == 1) __syncthreads();
        if (shift == s_) {
            const int q = l31;
#pragma unroll
            for (int dt = 0; dt < 2; ++dt)
#pragma unroll
                for (int rq = 0; rq < 4; ++rq) {
                    int d = dt * 32 + rq * 8 + 4 * lh;
                    u32 w0 = pk2(oacc[dt][rq * 4 + 0] * inv, oacc[dt][rq * 4 + 1] * inv);
                    u32 w1 = pk2(oacc[dt][rq * 4 + 2] * inv, oacc[dt][rq * 4 + 3] * inv);
                    int byte = q * 128 + ((d * 2) ^ ((q & 7) << 4));
                    *(u32*)((char*)ow + byte) = w0;
                    *(u32*)((char*)ow + byte + 4) = w1;
                }
#pragma unroll
            for (int i = 0; i < 4; ++i) {
                int qq = (lane >> 3) + i * 8;
                int byte = qq * 128 + (((lane & 7) * 16) ^ ((qq & 7) << 4));
                bf16x8 val = *(const bf16x8*)((char*)ow + byte);
                *(bf16x8*)(O + (q0 + qq) * 512 + h * 64 + (lane & 7) * 8) = val;
            }
        }
    }
}

// ---------------------------------------------------------------------------
// GroupNorm stats, coalesced two-stage.
// gn_part: grid (8 b, 64 chunks); block reads 64 full rows (coalesced),
// reduces to per-group partial sum/sq -> part[(b*64+ch)*64 + {g | 32+g}].
// gn_coef: 1 block, thread = b*32+g reduces 64 chunks -> coefA/coefD.
// ---------------------------------------------------------------------------
__global__ __launch_bounds__(256)
void gn_part(const float* __restrict__ x, float* __restrict__ part)
{
    const int b = blockIdx.x, ch = blockIdx.y;
    const float* base = x + ((long)b * 4096 + ch * 64) * 512;
    const int t = threadIdx.x;
    const int c4 = t & 127, r0 = t >> 7;
    float sum = 0.f, sq = 0.f;
    for (int rr = r0; rr < 64; rr += 2) {
        float4 v = *(const float4*)(base + (long)rr * 512 + c4 * 4);
        sum += v.x + v.y + v.z + v.w;
        sq  += v.x * v.x + v.y * v.y + v.z * v.z + v.w * v.w;
    }
    __shared__ float s0[128], s1[128];
    if (t >= 128) { s0[c4] = sum; s1[c4] = sq; }
    __syncthreads();
    if (t < 128) {
        sum += s0[c4]; sq += s1[c4];
        sum += __shfl_down(sum, 2); sum += __shfl_down(sum, 1);
        sq  += __shfl_down(sq, 2);  sq  += __shfl_down(sq, 1);
        if ((t & 3) == 0) {
            int g = t >> 2;
            float* pp = part + (long)(b * 64 + ch) * 64;
            pp[g] = sum; pp[32 + g] = sq;
        }
    }
}

__global__ __launch_bounds__(256)
void gn_coef(const float* __restrict__ part, const float* __restrict__ gscale,
             const float* __restrict__ gbias, float* __restrict__ coefA,
             float* __restrict__ coefD)
{
    const int t = threadIdx.x;
    const int b = t >> 5, g = t & 31;
    float S = 0.f, Q = 0.f;
    for (int ch = 0; ch < 64; ++ch) {
        const float* pp = part + (long)(b * 64 + ch) * 64;
        S += pp[g]; Q += pp[32 + g];
    }
    float mean = S * (1.f / 65536.f);
    float var = Q * (1.f / 65536.f) - mean * mean;
    float rstd = rsqrtf(var + 1e-5f);
#pragma unroll
    for (int cc = 0; cc < 16; ++cc) {
        int c = g * 16 + cc;
        float a = gscale[c] * rstd;
        coefA[b * 512 + c] = a;
        coefD[b * 512 + c] = gbias[c] - mean * a;
    }
}

// f32 -> bf16 bulk convert (n multiple of 8*256)
__global__ __launch_bounds__(256)
void conv_bf16(const float* __restrict__ in, u16* __restrict__ out)
{
    long e = ((long)blockIdx.x * 256 + threadIdx.x) * 8;
    float4 v0 = *(const float4*)(in + e);
    float4 v1 = *(const float4*)(in + e + 4);
    float f[8] = { v0.x, v0.y, v0.z, v0.w, v1.x, v1.y, v1.z, v1.w };
    u32x4 o;
#pragma unroll
    for (int q = 0; q < 4; ++q)
        o[q] = (u32)f2bf(f[q * 2]) | ((u32)f2bf(f[q * 2 + 1]) << 16);
    *(u32x4*)(out + e) = o;
}

// all 4 weight transposes in one launch: z selects matrix (f32 -> bf16)
__global__ __launch_bounds__(256)
void transpose_all(const float* __restrict__ Wq, const float* __restrict__ Wk,
                   const float* __restrict__ Wv, const float* __restrict__ Wo,
                   u16* __restrict__ WqT, u16* __restrict__ WkT,
                   u16* __restrict__ WvT, u16* __restrict__ WoT)
{
    __shared__ u16 t[32][33];
    const int z = blockIdx.z;
    const float* in = (z == 0) ? Wq : (z == 1) ? Wk : (z == 2) ? Wv : Wo;
    u16* out = (z == 0) ? WqT : (z == 1) ? WkT : (z == 2) ? WvT : WoT;
    const int R = (z == 1 || z == 2) ? 768 : 512, C = 512;
    const int r0 = blockIdx.y * 32, c0 = blockIdx.x * 32;
    if (r0 >= R) return;
    int tx = threadIdx.x & 31, ty = threadIdx.x >> 5;
    for (int i = ty; i < 32; i += 8) t[i][tx] = f2bf(in[(long)(r0 + i) * C + c0 + tx]);
    __syncthreads();
    for (int i = ty; i < 32; i += 8) out[(long)(c0 + i) * R + r0 + tx] = t[tx][i];
}

extern "C" void kernel_launch(void* const* d_in, const int* in_sizes, int n_in,
                              void* d_out, int out_size, void* d_ws, size_t ws_size,
                              hipStream_t stream)
{
    const float* x    = (const float*)d_in[0];
    const float* cond = (const float*)d_in[1];
    const float* gsc  = (const float*)d_in[2];
    const float* gbi  = (const float*)d_in[3];
    const float* Wq   = (const float*)d_in[4];
    const float* Wk   = (const float*)d_in[5];
    const float* Wv   = (const float*)d_in[6];
    const float* Wo   = (const float*)d_in[7];
    const float* bo   = (const float*)d_in[8];

    char* ws = (char*)d_ws;
    size_t off = 0;
    auto alloc = [&](size_t bytes) -> void* {
        void* p = ws + off; off += (bytes + 255) & ~(size_t)255; return p;
    };
    u16* WqT    = (u16*)alloc(512 * 512 * 2);
    u16* WkT    = (u16*)alloc(512 * 768 * 2);
    u16* WvT    = (u16*)alloc(512 * 768 * 2);
    u16* WoT    = (u16*)alloc(512 * 512 * 2);
    float* cfA  = (float*)alloc(8 * 512 * 4);
    float* cfD  = (float*)alloc(8 * 512 * 4);
    float* part = (float*)alloc(8 * 64 * 64 * 4);
    u16* condb  = (u16*)alloc(2048l * 768 * 2);
    u16* Ob     = (u16*)alloc(33554432);
    u16* Qb     = (u16*)alloc(33554432);
    u16* Kb     = (u16*)alloc(2048l * 512 * 2);
    u16* Vt     = (u16*)alloc(2097152);

    transpose_all<<<dim3(16, 24, 4), 256, 0, stream>>>(Wq, Wk, Wv, Wo, WqT, WkT, WvT, WoT);
    conv_bf16<<<768, 256, 0, stream>>>(cond, condb);

    gn_part<<<dim3(8, 64), 256, 0, stream>>>(x, part);
    gn_coef<<<1, 256, 0, stream>>>(part, gsc, gbi, cfA, cfD);

    // Q = (GN(x) @ WqT) * 0.125*log2(e)  — GN affine fused into A staging
    gemm_bt<0, false, false, true><<<dim3(256, 4), 256, 0, stream>>>(
        x, WqT, Qb, nullptr, nullptr, cfA, cfD, 512, 512, 512, 512,
        0.18033688011112042f);
    // K = cond @ WkT      (2048 x 512 x 768)
    gemm_bt<0, false, false, false><<<dim3(16, 4), 256, 0, stream>>>(
        condb, WkT, Kb, nullptr, nullptr, nullptr, nullptr, 768, 768, 768, 512, 1.f);
    // V = cond @ WvT, stored transposed per head -> Vt[b*8+h][64][256]
    gemm_bt<2, false, false, false><<<dim3(16, 4), 256, 0, stream>>>(
        condb, WvT, Vt, nullptr, nullptr, nullptr, nullptr, 768, 768, 768, 0, 1.f);

    // fused attention: scores+softmax+PV, writes Ob
    attn_fused<<<dim3(16, 64), 512, 0, stream>>>(Qb, Kb, Vt, Ob);

    // out = x + Ob @ WoT + bo    (32768 x 512 x 512), f32, coalesced epilogue
    gemm_bt<1, true, true, false><<<dim3(256, 4), 256, 0, stream>>>(
        Ob, WoT, d_out, bo, x, nullptr, nullptr, 512, 512, 512, 512, 1.f);
}

// Round 7
// 176.931 us; speedup vs baseline: 1.3518x; 1.1042x over previous
//
#include <hip/hip_runtime.h>
#include <hip/hip_bf16.h>

typedef unsigned short u16;
typedef unsigned int u32;
typedef __attribute__((ext_vector_type(8))) __bf16 bf16x8;
typedef __attribute__((ext_vector_type(4))) float f32x4;
typedef __attribute__((ext_vector_type(16))) float f32x16;
typedef __attribute__((ext_vector_type(4))) u32 u32x4;

#define DEVFN static __device__ __forceinline__

DEVFN float bf2f(u16 v) { union { u32 u; float f; } x; x.u = (u32)v << 16; return x.f; }
DEVFN u16 f2bf(float f) {
    union { float f; u32 u; } x; x.f = f;
    u32 r = x.u + 0x7fff + ((x.u >> 16) & 1);
    return (u16)(r >> 16);
}

union BF2 { struct { __bf16 lo, hi; } s; u32 w; };
DEVFN u32 pk2(float a, float b) { BF2 t; t.s.lo = (__bf16)a; t.s.hi = (__bf16)b; return t.w; }

DEVFN void gload_lds16(const u16* g, u16* l) {
    __builtin_amdgcn_global_load_lds((const __attribute__((address_space(1))) u32*)g,
                                     (__attribute__((address_space(3))) u32*)l, 16, 0, 0);
}

// ---------------------------------------------------------------------------
// C = A (M,K) @ B^T (N,K), bf16 MFMA, f32 accum. Tile 128x128, BK=32,
// 4 waves 2x2, wave tile 64x64. 2-phase double-buffered LDS (T3 minimum
// recipe): top-of-iter vmcnt(0)+barrier, then issue next-tile stage, then
// compute current tile. 16KB/buffer, 32KB total.
// OUTMODE: 0 = bf16 C (scaled); 1 = f32 C via coalesced LDS epilogue
// (+bias/residual); 2 = bf16 Vt store; 3 = z-select (z=0: bf16 C->Cv with
// weights B, z=1: Vt->Cv2 with weights B2).
// AFF: A is f32, GN affine applied during staging (T14 split: global->reg
// issued with B stage, convert+ds_write after MFMA), packed to bf16.
// ---------------------------------------------------------------------------
template<int OUTMODE, bool BIAS, bool RES, bool AFF>
__global__ __launch_bounds__(256)
void gemm_bt(const void* __restrict__ Av, const u16* __restrict__ B,
             const u16* __restrict__ B2,
             void* __restrict__ Cv, void* __restrict__ Cv2,
             const float* __restrict__ bias, const float* __restrict__ res,
             const float* __restrict__ cfA, const float* __restrict__ cfD,
             int K, int lda, int ldb, int ldc, float scale)
{
    __shared__ u16 smem[16384];  // 32KB: [bufA0 4K | bufB0 4K | bufA1 4K | bufB1 4K] u16
    const int tid = threadIdx.x;
    const int lane = tid & 63, wave = tid >> 6;
    const int wr = wave >> 1, wc = wave & 1;
    const u16* Bsel = (OUTMODE == 3 && blockIdx.z) ? B2 : B;
    const u16* Bb = Bsel + (long)blockIdx.y * 128 * ldb;
    const int ra = tid >> 2, ca = (tid & 3) * 8;       // staging row/col in pass
    const int foff = ((lane & 15) * 4 + (lane >> 4)) * 8;

    f32x4 acc[4][4];
#pragma unroll
    for (int i = 0; i < 4; ++i)
#pragma unroll
        for (int j = 0; j < 4; ++j) acc[i][j] = (f32x4){0.f, 0.f, 0.f, 0.f};

    const int nt = K >> 5;

    auto stageB = [&](int t, u16* bb) {
#pragma unroll
        for (int p = 0; p < 2; ++p)
            gload_lds16(Bb + (long)(p * 64 + ra) * ldb + t * 32 + ca,
                        bb + (p * 256 + tid) * 8);
    };
    const u16* Ab = (const u16*)Av + (long)blockIdx.x * 128 * lda;
    auto stageA = [&](int t, u16* ab) {
#pragma unroll
        for (int p = 0; p < 2; ++p)
            gload_lds16(Ab + (long)(p * 64 + ra) * lda + t * 32 + ca,
                        ab + (p * 256 + tid) * 8);
    };
    const float* xf = (const float*)Av;
    float4 xr[2][2], ar[2][2], dr[2][2];
    auto affLoad = [&](int t) {
#pragma unroll
        for (int p = 0; p < 2; ++p) {
            long m = (long)blockIdx.x * 128 + p * 64 + ra;
            int c = t * 32 + ca;
            const float* src = xf + m * lda + c;
            xr[p][0] = *(const float4*)(src);
            xr[p][1] = *(const float4*)(src + 4);
            int cb = (int)((m >> 12) << 9) + c;
            ar[p][0] = *(const float4*)(cfA + cb);
            ar[p][1] = *(const float4*)(cfA + cb + 4);
            dr[p][0] = *(const float4*)(cfD + cb);
            dr[p][1] = *(const float4*)(cfD + cb + 4);
        }
    };
    auto affWrite = [&](u16* ab) {
#pragma unroll
        for (int p = 0; p < 2; ++p) {
            u32x4 o;
            o[0] = pk2(xr[p][0].x * ar[p][0].x + dr[p][0].x,
                       xr[p][0].y * ar[p][0].y + dr[p][0].y);
            o[1] = pk2(xr[p][0].z * ar[p][0].z + dr[p][0].z,
                       xr[p][0].w * ar[p][0].w + dr[p][0].w);
            o[2] = pk2(xr[p][1].x * ar[p][1].x + dr[p][1].x,
                       xr[p][1].y * ar[p][1].y + dr[p][1].y);
            o[3] = pk2(xr[p][1].z * ar[p][1].z + dr[p][1].z,
                       xr[p][1].w * ar[p][1].w + dr[p][1].w);
            *(u32x4*)(ab + (p * 256 + tid) * 8) = o;
        }
    };

    // ---- prologue: stage tile 0 into buffer 0
    stageB(0, smem + 4096);
    if constexpr (AFF) { affLoad(0); affWrite(smem); }
    else               stageA(0, smem);

    int cur = 0;
    for (int t = 0; t < nt; ++t) {
        asm volatile("s_waitcnt vmcnt(0)" ::: "memory");
        __syncthreads();                       // buf[cur] ready for all waves
        const int nxt = cur ^ 1;
        u16* cA = smem + cur * 8192;
        u16* cB = smem + cur * 8192 + 4096;
        u16* nA = smem + nxt * 8192;
        u16* nB = smem + nxt * 8192 + 4096;
        const bool more = (t + 1 < nt);
        if (more) {                            // issue next-tile stage first
            stageB(t + 1, nB);
            if constexpr (AFF) affLoad(t + 1);
            else               stageA(t + 1, nA);
        }
        bf16x8 av[4], bv[4];
#pragma unroll
        for (int i = 0; i < 4; ++i) av[i] = *(const bf16x8*)(cA + (wr * 4 + i) * 512 + foff);
#pragma unroll
        for (int j = 0; j < 4; ++j) bv[j] = *(const bf16x8*)(cB + (wc * 4 + j) * 512 + foff);
        __builtin_amdgcn_s_setprio(1);
#pragma unroll
        for (int i = 0; i < 4; ++i)
#pragma unroll
            for (int j = 0; j < 4; ++j)
                acc[i][j] = __builtin_amdgcn_mfma_f32_16x16x32_bf16(av[i], bv[j], acc[i][j], 0, 0, 0);
        __builtin_amdgcn_s_setprio(0);
        if (more) { if constexpr (AFF) affWrite(nA); }  // write-late (T14)
        cur = nxt;
    }

    const int m0 = blockIdx.x * 128 + wr * 64 + (lane >> 4) * 4;
    const int n0 = blockIdx.y * 128 + wc * 64 + (lane & 15);
    if constexpr (OUTMODE == 0) {
        u16* Cb = (u16*)Cv;
#pragma unroll
        for (int i = 0; i < 4; ++i)
#pragma unroll
            for (int j = 0; j < 4; ++j) {
                int n = n0 + j * 16;
#pragma unroll
                for (int r = 0; r < 4; ++r) {
                    int m = m0 + i * 16 + r;
                    Cb[(long)m * ldc + n] = f2bf(acc[i][j][r] * scale);
                }
            }
    } else if constexpr (OUTMODE == 1) {
        // coalesced f32 epilogue through padded LDS (32 x 132), 4 row-chunks
        float* cl = (float*)smem;
        float* Co = (float*)Cv;
#pragma unroll
        for (int i = 0; i < 4; ++i) {
            __syncthreads();
#pragma unroll
            for (int j = 0; j < 4; ++j)
#pragma unroll
                for (int r = 0; r < 4; ++r) {
                    int rl = wr * 16 + (lane >> 4) * 4 + r;
                    int col = wc * 64 + j * 16 + (lane & 15);
                    cl[rl * 132 + col] = acc[i][j][r];
                }
            __syncthreads();
            int rl = tid >> 3;
            int c0 = (tid & 7) * 16;
            long m = (long)blockIdx.x * 128 + i * 16 + (rl & 15) + (rl >> 4) * 64;
            long n = (long)blockIdx.y * 128 + c0;
#pragma unroll
            for (int q = 0; q < 4; ++q) {
                float4 v = *(float4*)(cl + rl * 132 + c0 + q * 4);
                float4 o;
                o.x = v.x * scale; o.y = v.y * scale;
                o.z = v.z * scale; o.w = v.w * scale;
                if constexpr (BIAS) {
                    float4 b4 = *(const float4*)(bias + n + q * 4);
                    o.x += b4.x; o.y += b4.y; o.z += b4.z; o.w += b4.w;
                }
                if constexpr (RES) {
                    float4 r4 = *(const float4*)(res + m * ldc + n + q * 4);
                    o.x += r4.x; o.y += r4.y; o.z += r4.z; o.w += r4.w;
                }
                *(float4*)(Co + m * ldc + n + q * 4) = o;
            }
        }
    } else if constexpr (OUTMODE == 2) {
#pragma unroll
        for (int i = 0; i < 4; ++i) {
            int m = m0 + i * 16;
            int b = m >> 8, s = m & 255;
#pragma unroll
            for (int j = 0; j < 4; ++j) {
                int n = n0 + j * 16;
                int h = n >> 6, d = n & 63;
                ushort4 pk;
                pk.x = f2bf(acc[i][j][0]); pk.y = f2bf(acc[i][j][1]);
                pk.z = f2bf(acc[i][j][2]); pk.w = f2bf(acc[i][j][3]);
                *(ushort4*)((u16*)Cv + (((long)(b * 8 + h) * 64 + d) * 256 + s)) = pk;
            }
        }
    } else {  // OUTMODE == 3: z=0 bf16 C -> Cv; z=1 Vt -> Cv2
        if (blockIdx.z == 0) {
            u16* Cb = (u16*)Cv;
#pragma unroll
            for (int i = 0; i < 4; ++i)
#pragma unroll
                for (int j = 0; j < 4; ++j) {
                    int n = n0 + j * 16;
#pragma unroll
                    for (int r = 0; r < 4; ++r) {
                        int m = m0 + i * 16 + r;
                        Cb[(long)m * ldc + n] = f2bf(acc[i][j][r] * scale);
                    }
                }
        } else {
#pragma unroll
            for (int i = 0; i < 4; ++i) {
                int m = m0 + i * 16;
                int b = m >> 8, s = m & 255;
#pragma unroll
                for (int j = 0; j < 4; ++j) {
                    int n = n0 + j * 16;
                    int h = n >> 6, d = n & 63;
                    ushort4 pk;
                    pk.x = f2bf(acc[i][j][0]); pk.y = f2bf(acc[i][j][1]);
                    pk.z = f2bf(acc[i][j][2]); pk.w = f2bf(acc[i][j][3]);
                    *(ushort4*)((u16*)Cv2 + (((long)(b * 8 + h) * 64 + d) * 256 + s)) = pk;
                }
            }
        }
    }
}

// ---------------------------------------------------------------------------
// Fused attention v3 (unchanged, verified R5/R6): LDS-staged K/V + online
// softmax. grid (16, 64), 512 threads = 8 waves x 32 queries.
// ---------------------------------------------------------------------------
union U8 { u32 w[4]; bf16x8 v; };

__global__ __launch_bounds__(512, 4)
void attn_fused(const u16* __restrict__ Q, const u16* __restrict__ K,
                const u16* __restrict__ Vt, u16* __restrict__ O)
{
    __shared__ u16 lds[40960];  // 80KB
    const int tid = threadIdx.x, lane = tid & 63, wave = tid >> 6;
    const int bh = blockIdx.y, b = bh >> 3, h = bh & 7;
    const int l31 = lane & 31, lh = lane >> 5;
    const long q0 = (long)b * 4096 + blockIdx.x * 256 + wave * 32;
    const bool hiHalf = (lh != 0);

    {
        const u16* Kb_ = K + (long)b * 256 * 512 + h * 64;
        const u16* Vb_ = Vt + (long)bh * 16384;
#pragma unroll
        for (int it = 0; it < 4; ++it) {
            int f = it * 8 + wave;           // 0..31
            int st = f >> 2, kc = f & 3;
            gload_lds16(Kb_ + (long)(st * 32 + l31) * 512 + kc * 16 + lh * 8,
                        lds + f * 512 + lane * 8);
            int dt = f >> 4, ks = f & 15;
            gload_lds16(Vb_ + (long)(dt * 32 + l31) * 256 + ks * 16 + lh * 8,
                        lds + 16384 + f * 512 + lane * 8);
        }
    }
    bf16x8 qf[4];
    {
        const u16* Qp = Q + (q0 + l31) * 512 + h * 64 + lh * 8;
#pragma unroll
        for (int kc = 0; kc < 4; ++kc) qf[kc] = *(const bf16x8*)(Qp + kc * 16);
    }
    asm volatile("s_waitcnt vmcnt(0)" ::: "memory");
    __syncthreads();

    f32x16 oacc[2];
#pragma unroll
    for (int dt = 0; dt < 2; ++dt)
#pragma unroll
        for (int r = 0; r < 16; ++r) oacc[dt][r] = 0.f;
    float m_run = -3e38f, sum_run = 0.f;

#pragma unroll
    for (int st = 0; st < 8; ++st) {
        f32x16 sc;
#pragma unroll
        for (int r = 0; r < 16; ++r) sc[r] = 0.f;
        __builtin_amdgcn_s_setprio(1);
#pragma unroll
        for (int kc = 0; kc < 4; ++kc) {
            bf16x8 af = *(const bf16x8*)(lds + (st * 4 + kc) * 512 + lane * 8);
            sc = __builtin_amdgcn_mfma_f32_32x32x16_bf16(af, qf[kc], sc, 0, 0, 0);
        }
        __builtin_amdgcn_s_setprio(0);
        float tm = sc[0];
#pragma unroll
        for (int r = 1; r < 16; ++r) tm = fmaxf(tm, sc[r]);
        tm = fmaxf(tm, __shfl_xor(tm, 32));
        if (!__all(tm <= m_run + 8.f)) {
            float mnew = fmaxf(m_run, tm);
            float fac = exp2f(m_run - mnew);
            m_run = mnew;
            sum_run *= fac;
#pragma unroll
            for (int dt = 0; dt < 2; ++dt)
#pragma unroll
                for (int r = 0; r < 16; ++r) oacc[dt][r] *= fac;
        }
#pragma unroll
        for (int r = 0; r < 16; ++r) {
            float e = exp2f(sc[r] - m_run);
            sc[r] = e; sum_run += e;
        }
        u32 c[8], x[8];
#pragma unroll
        for (int i = 0; i < 8; ++i) c[i] = pk2(sc[2 * i], sc[2 * i + 1]);
#pragma unroll
        for (int i = 0; i < 8; ++i) x[i] = (u32)__shfl_xor((int)c[i], 32);
        U8 p0, p1;
        p0.w[0] = hiHalf ? x[2] : c[0];  p0.w[1] = hiHalf ? x[3] : c[1];
        p0.w[2] = hiHalf ? c[2] : x[0];  p0.w[3] = hiHalf ? c[3] : x[1];
        p1.w[0] = hiHalf ? x[6] : c[4];  p1.w[1] = hiHalf ? x[7] : c[5];
        p1.w[2] = hiHalf ? c[6] : x[4];  p1.w[3] = hiHalf ? c[7] : x[5];
        __builtin_amdgcn_s_setprio(1);
#pragma unroll
        for (int dt = 0; dt < 2; ++dt) {
            bf16x8 v0 = *(const bf16x8*)(lds + 16384 + (dt * 16 + st * 2) * 512 + lane * 8);
            bf16x8 v1 = *(const bf16x8*)(lds + 16384 + (dt * 16 + st * 2 + 1) * 512 + lane * 8);
            oacc[dt] = __builtin_amdgcn_mfma_f32_32x32x16_bf16(v0, p0.v, oacc[dt], 0, 0, 0);
            oacc[dt] = __builtin_amdgcn_mfma_f32_32x32x16_bf16(v1, p1.v, oacc[dt], 0, 0, 0);
        }
        __builtin_amdgcn_s_setprio(0);
    }

    sum_run += __shfl_xor(sum_run, 32);
    float inv = 1.f / sum_run;

    u16* ow = lds + 32768 + (wave & 3) * 2048;
    const int shift = wave >> 2;
#pragma unroll
    for (int s_ = 0; s_ < 2; ++s_) {
        if (s_ == 1) __syncthreads();
        if (shift == s_) {
            const int q = l31;
#pragma unroll
            for (int dt = 0; dt < 2; ++dt)
#pragma unroll
                for (int rq = 0; rq < 4; ++rq) {
                    int d = dt * 32 + rq * 8 + 4 * lh;
                    u32 w0 = pk2(oacc[dt][rq * 4 + 0] * inv, oacc[dt][rq * 4 + 1] * inv);
                    u32 w1 = pk2(oacc[dt][rq * 4 + 2] * inv, oacc[dt][rq * 4 + 3] * inv);
                    int byte = q * 128 + ((d * 2) ^ ((q & 7) << 4));
                    *(u32*)((char*)ow + byte) = w0;
                    *(u32*)((char*)ow + byte + 4) = w1;
                }
#pragma unroll
            for (int i = 0; i < 4; ++i) {
                int qq = (lane >> 3) + i * 8;
                int byte = qq * 128 + (((lane & 7) * 16) ^ ((qq & 7) << 4));
                bf16x8 val = *(const bf16x8*)((char*)ow + byte);
                *(bf16x8*)(O + (q0 + qq) * 512 + h * 64 + (lane & 7) * 8) = val;
            }
        }
    }
}

// ---------------------------------------------------------------------------
// GroupNorm stats, coalesced two-stage (unchanged, verified R6).
// ---------------------------------------------------------------------------
__global__ __launch_bounds__(256)
void gn_part(const float* __restrict__ x, float* __restrict__ part)
{
    const int b = blockIdx.x, ch = blockIdx.y;
    const float* base = x + ((long)b * 4096 + ch * 64) * 512;
    const int t = threadIdx.x;
    const int c4 = t & 127, r0 = t >> 7;
    float sum = 0.f, sq = 0.f;
    for (int rr = r0; rr < 64; rr += 2) {
        float4 v = *(const float4*)(base + (long)rr * 512 + c4 * 4);
        sum += v.x + v.y + v.z + v.w;
        sq  += v.x * v.x + v.y * v.y + v.z * v.z + v.w * v.w;
    }
    __shared__ float s0[128], s1[128];
    if (t >= 128) { s0[c4] = sum; s1[c4] = sq; }
    __syncthreads();
    if (t < 128) {
        sum += s0[c4]; sq += s1[c4];
        sum += __shfl_down(sum, 2); sum += __shfl_down(sum, 1);
        sq  += __shfl_down(sq, 2);  sq  += __shfl_down(sq, 1);
        if ((t & 3) == 0) {
            int g = t >> 2;
            float* pp = part + (long)(b * 64 + ch) * 64;
            pp[g] = sum; pp[32 + g] = sq;
        }
    }
}

__global__ __launch_bounds__(256)
void gn_coef(const float* __restrict__ part, const float* __restrict__ gscale,
             const float* __restrict__ gbias, float* __restrict__ coefA,
             float* __restrict__ coefD)
{
    const int t = threadIdx.x;
    const int b = t >> 5, g = t & 31;
    float S = 0.f, Q = 0.f;
    for (int ch = 0; ch < 64; ++ch) {
        const float* pp = part + (long)(b * 64 + ch) * 64;
        S += pp[g]; Q += pp[32 + g];
    }
    float mean = S * (1.f / 65536.f);
    float var = Q * (1.f / 65536.f) - mean * mean;
    float rstd = rsqrtf(var + 1e-5f);
#pragma unroll
    for (int cc = 0; cc < 16; ++cc) {
        int c = g * 16 + cc;
        float a = gscale[c] * rstd;
        coefA[b * 512 + c] = a;
        coefD[b * 512 + c] = gbias[c] - mean * a;
    }
}

// f32 -> bf16 bulk convert (n multiple of 8*256)
__global__ __launch_bounds__(256)
void conv_bf16(const float* __restrict__ in, u16* __restrict__ out)
{
    long e = ((long)blockIdx.x * 256 + threadIdx.x) * 8;
    float4 v0 = *(const float4*)(in + e);
    float4 v1 = *(const float4*)(in + e + 4);
    float f[8] = { v0.x, v0.y, v0.z, v0.w, v1.x, v1.y, v1.z, v1.w };
    u32x4 o;
#pragma unroll
    for (int q = 0; q < 4; ++q)
        o[q] = (u32)f2bf(f[q * 2]) | ((u32)f2bf(f[q * 2 + 1]) << 16);
    *(u32x4*)(out + e) = o;
}

// all 4 weight transposes in one launch: z selects matrix (f32 -> bf16)
__global__ __launch_bounds__(256)
void transpose_all(const float* __restrict__ Wq, const float* __restrict__ Wk,
                   const float* __restrict__ Wv, const float* __restrict__ Wo,
                   u16* __restrict__ WqT, u16* __restrict__ WkT,
                   u16* __restrict__ WvT, u16* __restrict__ WoT)
{
    __shared__ u16 t[32][33];
    const int z = blockIdx.z;
    const float* in = (z == 0) ? Wq : (z == 1) ? Wk : (z == 2) ? Wv : Wo;
    u16* out = (z == 0) ? WqT : (z == 1) ? WkT : (z == 2) ? WvT : WoT;
    const int R = (z == 1 || z == 2) ? 768 : 512, C = 512;
    const int r0 = blockIdx.y * 32, c0 = blockIdx.x * 32;
    if (r0 >= R) return;
    int tx = threadIdx.x & 31, ty = threadIdx.x >> 5;
    for (int i = ty; i < 32; i += 8) t[i][tx] = f2bf(in[(long)(r0 + i) * C + c0 + tx]);
    __syncthreads();
    for (int i = ty; i < 32; i += 8) out[(long)(c0 + i) * R + r0 + tx] = t[tx][i];
}

extern "C" void kernel_launch(void* const* d_in, const int* in_sizes, int n_in,
                              void* d_out, int out_size, void* d_ws, size_t ws_size,
                              hipStream_t stream)
{
    const float* x    = (const float*)d_in[0];
    const float* cond = (const float*)d_in[1];
    const float* gsc  = (const float*)d_in[2];
    const float* gbi  = (const float*)d_in[3];
    const float* Wq   = (const float*)d_in[4];
    const float* Wk   = (const float*)d_in[5];
    const float* Wv   = (const float*)d_in[6];
    const float* Wo   = (const float*)d_in[7];
    const float* bo   = (const float*)d_in[8];

    char* ws = (char*)d_ws;
    size_t off = 0;
    auto alloc = [&](size_t bytes) -> void* {
        void* p = ws + off; off += (bytes + 255) & ~(size_t)255; return p;
    };
    u16* WqT    = (u16*)alloc(512 * 512 * 2);
    u16* WkT    = (u16*)alloc(512 * 768 * 2);
    u16* WvT    = (u16*)alloc(512 * 768 * 2);
    u16* WoT    = (u16*)alloc(512 * 512 * 2);
    float* cfA  = (float*)alloc(8 * 512 * 4);
    float* cfD  = (float*)alloc(8 * 512 * 4);
    float* part = (float*)alloc(8 * 64 * 64 * 4);
    u16* condb  = (u16*)alloc(2048l * 768 * 2);
    u16* Ob     = (u16*)alloc(33554432);
    u16* Qb     = (u16*)alloc(33554432);
    u16* Kb     = (u16*)alloc(2048l * 512 * 2);
    u16* Vt     = (u16*)alloc(2097152);

    transpose_all<<<dim3(16, 24, 4), 256, 0, stream>>>(Wq, Wk, Wv, Wo, WqT, WkT, WvT, WoT);
    conv_bf16<<<768, 256, 0, stream>>>(cond, condb);

    gn_part<<<dim3(8, 64), 256, 0, stream>>>(x, part);
    gn_coef<<<1, 256, 0, stream>>>(part, gsc, gbi, cfA, cfD);

    // Q = (GN(x) @ WqT) * 0.125*log2(e)  — GN affine fused into A staging
    gemm_bt<0, false, false, true><<<dim3(256, 4), 256, 0, stream>>>(
        x, WqT, nullptr, Qb, nullptr, nullptr, nullptr, cfA, cfD,
        512, 512, 512, 512, 0.18033688011112042f);
    // K and V in one launch (z=0: K->Kb; z=1: V->Vt transposed per head)
    gemm_bt<3, false, false, false><<<dim3(16, 4, 2), 256, 0, stream>>>(
        condb, WkT, WvT, Kb, Vt, nullptr, nullptr, nullptr, nullptr,
        768, 768, 768, 512, 1.f);

    // fused attention: scores+softmax+PV, writes Ob
    attn_fused<<<dim3(16, 64), 512, 0, stream>>>(Qb, Kb, Vt, Ob);

    // out = x + Ob @ WoT + bo    (32768 x 512 x 512), f32, coalesced epilogue
    gemm_bt<1, true, true, false><<<dim3(256, 4), 256, 0, stream>>>(
        Ob, WoT, nullptr, d_out, nullptr, bo, x, nullptr, nullptr,
        512, 512, 512, 512, 1.f);
}